// Round 8
// baseline (921.156 us; speedup 1.0000x reference)
//
#include <hip/hip_runtime.h>
#include <hip/hip_bf16.h>

// ---------------- constants ----------------
#define Btok 16384
#define Ddim 1024
#define Eexp 8

typedef __attribute__((ext_vector_type(8))) short short8;
typedef __attribute__((ext_vector_type(4))) float f32x4;

__device__ inline unsigned short f2bf(float f) {
    unsigned int u = __float_as_uint(f);
    unsigned int r = (u + 0x7fffu + ((u >> 16) & 1u)) >> 16;
    return (unsigned short)r;
}

#define MEMF() asm volatile("" ::: "memory")
#define BARRIER() do { MEMF(); __builtin_amdgcn_s_barrier(); MEMF(); } while (0)
#define LGKM0() asm volatile("s_waitcnt lgkmcnt(0)" ::: "memory")

// ---------------- tiny precompute kernels (f64 accum for gate accuracy) ----------------
__global__ __launch_bounds__(256) void k_tmp(const float* __restrict__ Wo,
                                             const float* __restrict__ Wg,
                                             float* __restrict__ tmp) {
    int id = blockIdx.x * 256 + threadIdx.x;   // 8192
    int d = id >> 3, e = id & 7;
    double s = 0.0;
    for (int k = 0; k < Ddim; ++k)
        s += (double)Wo[(long)d * Ddim + k] * (double)Wg[k * Eexp + e];
    tmp[id] = (float)s;
}

__global__ __launch_bounds__(256) void k_wc(const float* __restrict__ Wv,
                                            const float* __restrict__ tmp,
                                            float* __restrict__ WcT) {
    int id = blockIdx.x * 256 + threadIdx.x;   // 8192
    int d = id >> 3, e = id & 7;
    double s = 0.0;
    for (int k = 0; k < Ddim; ++k)
        s += (double)Wv[(long)d * Ddim + k] * (double)tmp[k * Eexp + e];
    WcT[e * Ddim + d] = (float)s;
}

__global__ __launch_bounds__(512) void k_bc(const float* __restrict__ bv,
                                            const float* __restrict__ bo,
                                            const float* __restrict__ bg,
                                            const float* __restrict__ Wg,
                                            const float* __restrict__ tmp,
                                            float* __restrict__ bcomb) {
    int w = threadIdx.x >> 6, l = threadIdx.x & 63;
    double s = 0.0;
    for (int k = l; k < Ddim; k += 64)
        s += (double)bv[k] * (double)tmp[k * Eexp + w] +
             (double)bo[k] * (double)Wg[k * Eexp + w];
    #pragma unroll
    for (int off = 32; off; off >>= 1) s += __shfl_xor(s, off);
    if (l == 0) bcomb[w] = (float)s + bg[w];
}

// ---------------- conversions ----------------
__global__ __launch_bounds__(256) void k_convx(const float4* __restrict__ x,
                                               ushort4* __restrict__ xb) {
    int i = blockIdx.x * 256 + threadIdx.x;
    float4 v = x[i];
    ushort4 o;
    o.x = f2bf(v.x); o.y = f2bf(v.y); o.z = f2bf(v.z); o.w = f2bf(v.w);
    xb[i] = o;
}

__global__ __launch_bounds__(256) void k_convw(const float* __restrict__ W1,
                                               const float* __restrict__ W2,
                                               unsigned short* __restrict__ w1bT,
                                               unsigned short* __restrict__ w2bT) {
    __shared__ float tile[32][33];
    int bid = blockIdx.x;             // 2*8*32*32 = 16384
    int arr = bid >> 13;
    int e = (bid >> 10) & 7, bi = (bid >> 5) & 31, bj = bid & 31;
    const float* src = (arr ? W2 : W1) + (long)e * Ddim * Ddim;
    unsigned short* dst = (arr ? w2bT : w1bT) + (long)e * Ddim * Ddim;
    int tr = threadIdx.x >> 5, tc = threadIdx.x & 31;
    #pragma unroll
    for (int i = 0; i < 4; ++i) {
        int dl = tr + i * 8;
        tile[dl][tc] = src[(long)(bi * 32 + dl) * Ddim + bj * 32 + tc];
    }
    __syncthreads();
    #pragma unroll
    for (int i = 0; i < 4; ++i) {
        int nl = tr + i * 8;
        dst[(long)(bj * 32 + nl) * Ddim + bi * 32 + tc] = f2bf(tile[tc][nl]);
    }
}

// ---------------- gate: logits -> softmax -> top2 (NO atomics) ----------------
__global__ __launch_bounds__(256) void k_gate(const float* __restrict__ q,
                                              const float* __restrict__ WcT,
                                              const float* __restrict__ bcomb,
                                              float* __restrict__ gate_prob,
                                              int* __restrict__ choice,
                                              float2* __restrict__ w12,
                                              float* __restrict__ impP) {
    __shared__ float impL[4][8];
    int w = threadIdx.x >> 6, l = threadIdx.x & 63;
    int t = blockIdx.x * 4 + w;
    const float* qr = q + (long)t * Ddim;
    float acc[8] = {0, 0, 0, 0, 0, 0, 0, 0};
    #pragma unroll
    for (int i = 0; i < 4; ++i) {
        float4 qv = *(const float4*)(qr + (i * 64 + l) * 4);
        #pragma unroll
        for (int e = 0; e < 8; ++e) {
            float4 wv = *(const float4*)(WcT + e * Ddim + (i * 64 + l) * 4);
            acc[e] += qv.x * wv.x + qv.y * wv.y + qv.z * wv.z + qv.w * wv.w;
        }
    }
    #pragma unroll
    for (int off = 32; off; off >>= 1)
        #pragma unroll
        for (int e = 0; e < 8; ++e) acc[e] += __shfl_xor(acc[e], off);
    float lg[8], p[8];
    float m = -1e30f;
    #pragma unroll
    for (int e = 0; e < 8; ++e) { lg[e] = acc[e] + bcomb[e]; m = fmaxf(m, lg[e]); }
    float s = 0.f;
    #pragma unroll
    for (int e = 0; e < 8; ++e) { p[e] = expf(lg[e] - m); s += p[e]; }
    float inv = 1.f / s;
    #pragma unroll
    for (int e = 0; e < 8; ++e) p[e] *= inv;
    float p1 = -1.f, p2 = -1.f; int i1 = 0, i2 = 0;
    #pragma unroll
    for (int e = 0; e < 8; ++e) {
        float pe = p[e];
        if (pe > p1) { p2 = p1; i2 = i1; p1 = pe; i1 = e; }
        else if (pe > p2) { p2 = pe; i2 = e; }
    }
    float ee = expf(p2 - p1);
    float wa = 1.f / (1.f + ee);
    float wb = ee / (1.f + ee);
    if (l == 0) {
        #pragma unroll
        for (int e = 0; e < 8; ++e) gate_prob[(long)t * 8 + e] = p[e];
        #pragma unroll
        for (int e = 0; e < 8; ++e) impL[w][e] = p[e];
        choice[t] = i1 | (i2 << 8);
        w12[t] = make_float2(wa, wb);
    }
    __syncthreads();
    if (threadIdx.x < 8)
        impP[blockIdx.x * 8 + threadIdx.x] =
            impL[0][threadIdx.x] + impL[1][threadIdx.x] +
            impL[2][threadIdx.x] + impL[3][threadIdx.x];
}

// ---------------- sorted routing: histogram -> scan -> stable scatter ----------------
__global__ __launch_bounds__(256) void k_hist(const int* __restrict__ choice,
                                              int* __restrict__ bcnt) {
    __shared__ int cnt[8];
    if (threadIdx.x < 8) cnt[threadIdx.x] = 0;
    __syncthreads();
    int ch = choice[blockIdx.x * 256 + threadIdx.x];
    atomicAdd(&cnt[ch & 255], 1);
    atomicAdd(&cnt[(ch >> 8) & 255], 1);
    __syncthreads();
    if (threadIdx.x < 8) bcnt[blockIdx.x * 8 + threadIdx.x] = cnt[threadIdx.x];
}

__global__ __launch_bounds__(512) void k_scan(const int* __restrict__ bcnt,
                                              int* __restrict__ bbase,
                                              int* __restrict__ counts) {
    int w = threadIdx.x >> 6, l = threadIdx.x & 63;   // wave w = expert w
    int v = bcnt[l * 8 + w];
    int s = v;
    #pragma unroll
    for (int off = 1; off < 64; off <<= 1) {
        int o = __shfl_up(s, off);
        if (l >= off) s += o;
    }
    bbase[l * 8 + w] = s - v;
    if (l == 63) counts[w] = s;
}

__global__ __launch_bounds__(256) void k_scatter(const int* __restrict__ choice,
                                                 const float2* __restrict__ w12,
                                                 const int* __restrict__ bbase,
                                                 int* __restrict__ tok,
                                                 float* __restrict__ wgt) {
    __shared__ int wsum[4];
    int w = threadIdx.x >> 6, l = threadIdx.x & 63;
    int t = blockIdx.x * 256 + threadIdx.x;
    int ch = choice[t];
    int i1 = ch & 255, i2 = (ch >> 8) & 255;
    float2 ww = w12[t];
    for (int e = 0; e < 8; ++e) {
        bool f1 = (i1 == e), f2 = (i2 == e);
        bool f = f1 || f2;
        unsigned long long m = __ballot(f);
        int wl = __popcll(m & ((1ull << l) - 1ull));
        if (l == 0) wsum[w] = (int)__popcll(m);
        __syncthreads();
        int before = 0;
        #pragma unroll
        for (int j = 0; j < 4; ++j) before += (j < w) ? wsum[j] : 0;
        if (f) {
            int p = bbase[blockIdx.x * 8 + e] + before + wl;
            tok[e * Btok + p] = t;
            wgt[e * Btok + p] = f1 ? ww.x : ww.y;
        }
        __syncthreads();
    }
}

// ---------------- expert GEMMs: R5 shell + reg-staged async prefetch (T14) ----------------
// 128x128 tile, BK=64, 4 waves, 32KB LDS single buffer, 4 blocks/CU.
// Staging: global->reg (tile k+1 issued during tile k compute) -> ds_write after
// read-done barrier. Raw s_barrier (no vmcnt drain); load tail latency hidden
// behind a full K-tile of compute. XOR swizzle applied at ds_write + ds_read.
// MODE 0: H = bf16(silu(xb[tok] @ W1T + b1));  MODE 1: y[tok] += wgt*(H @ W2T + b2)
template <int MODE>
__global__ __launch_bounds__(256, 4) void k_gemm(const unsigned short* __restrict__ Abase,
                                                 const unsigned short* __restrict__ WT,
                                                 const float* __restrict__ bias,
                                                 const int* __restrict__ counts,
                                                 const int* __restrict__ tok,
                                                 const float* __restrict__ wgt,
                                                 unsigned short* __restrict__ Hout,
                                                 float* __restrict__ y) {
    __shared__ __align__(16) char lds[32768];   // A[128][128B] @0, B @16384
    char* ldsp = (char*)lds;

    int bid = blockIdx.x;                 // 4096 = 8e * 64rt * 8ct ; e=bid&7 -> XCD pin
    int e = bid & 7;
    int k = bid >> 3;
    int rt = k >> 3, ct = k & 7;

    int n_e = counts[e];
    int r0 = rt * 128;
    if (r0 >= n_e) return;
    int off_e = 0;
    #pragma unroll
    for (int j = 0; j < 8; ++j) off_e += (j < e) ? counts[j] : 0;
    int n0 = ct * 128;

    int t = threadIdx.x;
    int w = t >> 6, l = t & 63;
    int wm = w >> 1, wn = w & 1;          // wave tile 64x64

    // ---- staging addressing: thread t covers rows tr+32*ri, chunk (t&7) ----
    int tr = t >> 3;                      // 0..31
    int ch = t & 7;                       // natural 16B-chunk (coalesced reads)
    const char* sA[4]; const char* sB[4];
    #pragma unroll
    for (int ri = 0; ri < 4; ++ri) {
        int idx = r0 + ri * 32 + tr; if (idx > n_e - 1) idx = n_e - 1;
        long g = (MODE == 0) ? (long)tok[e * Btok + idx] : (long)(off_e + idx);
        sA[ri] = (const char*)Abase + g * 2048 + ch * 16;
        sB[ri] = (const char*)WT + ((long)e << 21) + (long)(n0 + ri * 32 + tr) * 2048 + ch * 16;
    }
    // ds_write dest (XOR swizzle on write): row*128 + (ch ^ (row&7))*16
    int pc = ch ^ (tr & 7);               // (row&7) == (tr&7) since rows step by 32
    int dst[4];
    #pragma unroll
    for (int ri = 0; ri < 4; ++ri) dst[ri] = (ri * 32 + tr) * 128 + pc * 16;

    // ---- fragment-read constants (same XOR on read) ----
    int rA = (wm * 64 + (l & 15)) * 128;
    int rB = (wn * 64 + (l & 15)) * 128;
    int x0 = ((l >> 4) ^ (l & 7)) << 4;
    int x1 = (((l >> 4) + 4) ^ (l & 7)) << 4;

    f32x4 acc[4][4];
    #pragma unroll
    for (int mi = 0; mi < 4; ++mi)
        #pragma unroll
        for (int ni = 0; ni < 4; ++ni) acc[mi][ni] = {0.f, 0.f, 0.f, 0.f};

    int4 stg[8];                          // staging regs (static indices only)

#define LOADT(kt) do { \
        _Pragma("unroll") \
        for (int ri_ = 0; ri_ < 4; ++ri_) { \
            stg[ri_]     = *(const int4*)(sA[ri_] + (kt) * 128); \
            stg[ri_ + 4] = *(const int4*)(sB[ri_] + (kt) * 128); \
        } } while (0)
#define DSWRITE() do { \
        _Pragma("unroll") \
        for (int ri_ = 0; ri_ < 4; ++ri_) { \
            *(int4*)(ldsp + dst[ri_])         = stg[ri_]; \
            *(int4*)(ldsp + 16384 + dst[ri_]) = stg[ri_ + 4]; \
        } } while (0)

    const int NT = Ddim / 64;             // 16 K-tiles
    // prologue: tile0 -> regs -> LDS; issue tile1 -> regs
    LOADT(0);
    DSWRITE();                            // compiler waits vmcnt per-reg
    LOADT(1);
    LGKM0();                              // ds_writes complete
    BARRIER();                            // tile0 visible

    for (int kt = 0; kt < NT; ++kt) {
        // ---- compute tile kt from LDS ----
        #pragma unroll
        for (int ks = 0; ks < 2; ++ks) {
            int xo = ks ? x1 : x0;
            short8 av[4], bv[4];
            #pragma unroll
            for (int mi = 0; mi < 4; ++mi)
                av[mi] = *(const short8*)(ldsp + rA + mi * 2048 + xo);
            #pragma unroll
            for (int ni = 0; ni < 4; ++ni)
                bv[ni] = *(const short8*)(ldsp + 16384 + rB + ni * 2048 + xo);
            __builtin_amdgcn_s_setprio(1);
            #pragma unroll
            for (int mi = 0; mi < 4; ++mi)
                #pragma unroll
                for (int ni = 0; ni < 4; ++ni)
                    acc[mi][ni] = __builtin_amdgcn_mfma_f32_16x16x32_bf16(av[mi], bv[ni], acc[mi][ni], 0, 0, 0);
            __builtin_amdgcn_s_setprio(0);
        }
        if (kt == NT - 1) break;
        BARRIER();                        // all waves done reading tile kt
        DSWRITE();                        // tile kt+1 regs -> LDS (auto vmcnt)
        if (kt < NT - 2) LOADT(kt + 2);   // issue next-next tile
        LGKM0();                          // this wave's ds_writes complete
        BARRIER();                        // tile kt+1 visible to all
    }
#undef LOADT
#undef DSWRITE

    // ---- epilogue ----
    float bias4[4];
    #pragma unroll
    for (int ni = 0; ni < 4; ++ni)
        bias4[ni] = bias[e * Ddim + n0 + wn * 64 + ni * 16 + (l & 15)];

    #pragma unroll
    for (int mi = 0; mi < 4; ++mi) {
        #pragma unroll
        for (int j = 0; j < 4; ++j) {
            int rl = wm * 64 + mi * 16 + (l >> 4) * 4 + j;
            int r = r0 + rl;
            bool ok = r < n_e;
            int trow = 0; float wr = 0.f;
            if (MODE == 1) {
                int ri = ok ? r : 0;
                trow = tok[e * Btok + ri];
                wr = wgt[e * Btok + ri];
            }
            #pragma unroll
            for (int ni = 0; ni < 4; ++ni) {
                int col = n0 + wn * 64 + ni * 16 + (l & 15);
                float v = acc[mi][ni][j] + bias4[ni];
                if (MODE == 0) {
                    v = v / (1.f + __expf(-v));   // silu
                    if (ok) Hout[(long)(off_e + r) * Ddim + col] = f2bf(v);
                } else {
                    if (ok) atomicAdd(&y[(long)trow * Ddim + col], wr * v);
                }
            }
        }
    }
}

// ---------------- importance loss ----------------
__global__ __launch_bounds__(256) void k_loss(const float* __restrict__ impP,
                                              float* __restrict__ out) {
    __shared__ float red[256];
    __shared__ float impF[8];
    for (int e = 0; e < 8; ++e) {
        float s = 0.f;
        for (int i = threadIdx.x; i < 4096; i += 256) s += impP[i * 8 + e];
        red[threadIdx.x] = s;
        __syncthreads();
        for (int st = 128; st > 0; st >>= 1) {
            if ((int)threadIdx.x < st) red[threadIdx.x] += red[threadIdx.x + st];
            __syncthreads();
        }
        if (threadIdx.x == 0) impF[e] = red[0];
        __syncthreads();
    }
    if (threadIdx.x == 0) {
        double mean = 0.0;
        for (int e = 0; e < 8; ++e) mean += (double)impF[e];
        mean /= 8.0;
        double var = 0.0;
        for (int e = 0; e < 8; ++e) {
            double d = (double)impF[e] - mean;
            var += d * d;
        }
        var /= 7.0;   // ddof=1
        out[0] = (float)(0.01 * var / (mean * mean));
    }
}

// ---------------- launch ----------------
extern "C" void kernel_launch(void* const* d_in, const int* in_sizes, int n_in,
                              void* d_out, int out_size, void* d_ws, size_t ws_size,
                              hipStream_t stream) {
    const float* x  = (const float*)d_in[0];
    const float* q  = (const float*)d_in[1];
    const float* Wv = (const float*)d_in[2];
    const float* bv = (const float*)d_in[3];
    const float* Wo = (const float*)d_in[4];
    const float* bo = (const float*)d_in[5];
    const float* Wg = (const float*)d_in[6];
    const float* bg = (const float*)d_in[7];
    const float* W1 = (const float*)d_in[8];
    const float* b1 = (const float*)d_in[9];
    const float* W2 = (const float*)d_in[10];
    const float* b2 = (const float*)d_in[11];

    float* y = (float*)d_out;                       // [16384][1024]
    float* gate_prob = y + (long)Btok * Ddim;       // [16384][8]
    float* loss = gate_prob + (long)Btok * Eexp;    // [1]

    char* ws = (char*)d_ws;
    int*   counts = (int*)(ws + 0);                           // 32 B
    float* bcomb  = (float*)(ws + 256);                       // 32 B
    float* tmp    = (float*)(ws + 512);                       // 32 KB
    float* WcT    = (float*)(ws + 33280);                     // 32 KB
    float* impP   = (float*)(ws + 66048);                     // 128 KB
    int*   choice = (int*)(ws + 197120);                      // 64 KB
    float2* w12   = (float2*)(ws + 262656);                   // 128 KB
    int*   tok    = (int*)(ws + 393728);                      // 512 KB
    float* wgt    = (float*)(ws + 918016);                    // 512 KB
    int*   bcnt   = (int*)(ws + 1442304);                     // 2 KB
    int*   bbase  = (int*)(ws + 1444352);                     // 2 KB
    unsigned short* xb   = (unsigned short*)(ws + 1446912);   // 32 MB
    unsigned short* w1bT = (unsigned short*)(ws + 35001344);  // 16 MB
    unsigned short* w2bT = (unsigned short*)(ws + 51778560);  // 16 MB
    unsigned short* H    = (unsigned short*)(ws + 68555776);  // 64 MB

    hipMemsetAsync(y, 0, (size_t)Btok * Ddim * sizeof(float), stream);

    k_tmp<<<32, 256, 0, stream>>>(Wo, Wg, tmp);
    k_wc <<<32, 256, 0, stream>>>(Wv, tmp, WcT);
    k_bc <<<1, 512, 0, stream>>>(bv, bo, bg, Wg, tmp, bcomb);
    k_convx<<<16384, 256, 0, stream>>>((const float4*)x, (ushort4*)xb);
    k_convw<<<16384, 256, 0, stream>>>(W1, W2, w1bT, w2bT);
    k_gate<<<4096, 256, 0, stream>>>(q, WcT, bcomb, gate_prob, choice, w12, impP);
    k_hist<<<64, 256, 0, stream>>>(choice, bcnt);
    k_scan<<<1, 512, 0, stream>>>(bcnt, bbase, counts);
    k_scatter<<<64, 256, 0, stream>>>(choice, w12, bbase, tok, wgt);
    k_gemm<0><<<4096, 256, 0, stream>>>(xb, w1bT, b1, counts, tok, wgt, H, nullptr);
    k_gemm<1><<<4096, 256, 0, stream>>>(H, w2bT, b2, counts, tok, wgt, nullptr, y);
    k_loss<<<1, 256, 0, stream>>>(impP, loss);
}

// Round 9
// 456.105 us; speedup vs baseline: 2.0196x; 2.0196x over previous
//
#include <hip/hip_runtime.h>
#include <hip/hip_bf16.h>

// ---------------- constants ----------------
#define Btok 16384
#define Ddim 1024
#define Eexp 8

typedef __attribute__((ext_vector_type(8))) short short8;
typedef __attribute__((ext_vector_type(4))) float f32x4;

__device__ inline unsigned short f2bf(float f) {
    unsigned int u = __float_as_uint(f);
    unsigned int r = (u + 0x7fffu + ((u >> 16) & 1u)) >> 16;
    return (unsigned short)r;
}

__device__ inline void gload16(const void* g, void* l) {
    __builtin_amdgcn_global_load_lds(
        (const __attribute__((address_space(1))) void*)g,
        (__attribute__((address_space(3))) void*)l, 16, 0, 0);
}

#define MEMF() asm volatile("" ::: "memory")
#define BARRIER() do { MEMF(); __builtin_amdgcn_s_barrier(); MEMF(); } while (0)
#define VMW(n) do { asm volatile("s_waitcnt vmcnt(" #n ")" ::: "memory"); \
                    __builtin_amdgcn_sched_barrier(0); } while (0)

// ---------------- tiny precompute kernels (f64 accum for gate accuracy) ----------------
__global__ __launch_bounds__(256) void k_tmp(const float* __restrict__ Wo,
                                             const float* __restrict__ Wg,
                                             float* __restrict__ tmp) {
    int id = blockIdx.x * 256 + threadIdx.x;   // 8192
    int d = id >> 3, e = id & 7;
    double s = 0.0;
    for (int k = 0; k < Ddim; ++k)
        s += (double)Wo[(long)d * Ddim + k] * (double)Wg[k * Eexp + e];
    tmp[id] = (float)s;
}

__global__ __launch_bounds__(256) void k_wc(const float* __restrict__ Wv,
                                            const float* __restrict__ tmp,
                                            float* __restrict__ WcT) {
    int id = blockIdx.x * 256 + threadIdx.x;   // 8192
    int d = id >> 3, e = id & 7;
    double s = 0.0;
    for (int k = 0; k < Ddim; ++k)
        s += (double)Wv[(long)d * Ddim + k] * (double)tmp[k * Eexp + e];
    WcT[e * Ddim + d] = (float)s;
}

__global__ __launch_bounds__(512) void k_bc(const float* __restrict__ bv,
                                            const float* __restrict__ bo,
                                            const float* __restrict__ bg,
                                            const float* __restrict__ Wg,
                                            const float* __restrict__ tmp,
                                            float* __restrict__ bcomb) {
    int w = threadIdx.x >> 6, l = threadIdx.x & 63;
    double s = 0.0;
    for (int k = l; k < Ddim; k += 64)
        s += (double)bv[k] * (double)tmp[k * Eexp + w] +
             (double)bo[k] * (double)Wg[k * Eexp + w];
    #pragma unroll
    for (int off = 32; off; off >>= 1) s += __shfl_xor(s, off);
    if (l == 0) bcomb[w] = (float)s + bg[w];
}

// ---------------- conversions ----------------
__global__ __launch_bounds__(256) void k_convx(const float4* __restrict__ x,
                                               ushort4* __restrict__ xb) {
    int i = blockIdx.x * 256 + threadIdx.x;
    float4 v = x[i];
    ushort4 o;
    o.x = f2bf(v.x); o.y = f2bf(v.y); o.z = f2bf(v.z); o.w = f2bf(v.w);
    xb[i] = o;
}

__global__ __launch_bounds__(256) void k_convw(const float* __restrict__ W1,
                                               const float* __restrict__ W2,
                                               unsigned short* __restrict__ w1bT,
                                               unsigned short* __restrict__ w2bT) {
    __shared__ float tile[32][33];
    int bid = blockIdx.x;             // 2*8*32*32 = 16384
    int arr = bid >> 13;
    int e = (bid >> 10) & 7, bi = (bid >> 5) & 31, bj = bid & 31;
    const float* src = (arr ? W2 : W1) + (long)e * Ddim * Ddim;
    unsigned short* dst = (arr ? w2bT : w1bT) + (long)e * Ddim * Ddim;
    int tr = threadIdx.x >> 5, tc = threadIdx.x & 31;
    #pragma unroll
    for (int i = 0; i < 4; ++i) {
        int dl = tr + i * 8;
        tile[dl][tc] = src[(long)(bi * 32 + dl) * Ddim + bj * 32 + tc];
    }
    __syncthreads();
    #pragma unroll
    for (int i = 0; i < 4; ++i) {
        int nl = tr + i * 8;
        dst[(long)(bj * 32 + nl) * Ddim + bi * 32 + tc] = f2bf(tile[tc][nl]);
    }
}

// ---------------- gate: logits -> softmax -> top2 (NO atomics) ----------------
__global__ __launch_bounds__(256) void k_gate(const float* __restrict__ q,
                                              const float* __restrict__ WcT,
                                              const float* __restrict__ bcomb,
                                              float* __restrict__ gate_prob,
                                              int* __restrict__ choice,
                                              float2* __restrict__ w12,
                                              float* __restrict__ impP) {
    __shared__ float impL[4][8];
    int w = threadIdx.x >> 6, l = threadIdx.x & 63;
    int t = blockIdx.x * 4 + w;
    const float* qr = q + (long)t * Ddim;
    float acc[8] = {0, 0, 0, 0, 0, 0, 0, 0};
    #pragma unroll
    for (int i = 0; i < 4; ++i) {
        float4 qv = *(const float4*)(qr + (i * 64 + l) * 4);
        #pragma unroll
        for (int e = 0; e < 8; ++e) {
            float4 wv = *(const float4*)(WcT + e * Ddim + (i * 64 + l) * 4);
            acc[e] += qv.x * wv.x + qv.y * wv.y + qv.z * wv.z + qv.w * wv.w;
        }
    }
    #pragma unroll
    for (int off = 32; off; off >>= 1)
        #pragma unroll
        for (int e = 0; e < 8; ++e) acc[e] += __shfl_xor(acc[e], off);
    float lg[8], p[8];
    float m = -1e30f;
    #pragma unroll
    for (int e = 0; e < 8; ++e) { lg[e] = acc[e] + bcomb[e]; m = fmaxf(m, lg[e]); }
    float s = 0.f;
    #pragma unroll
    for (int e = 0; e < 8; ++e) { p[e] = expf(lg[e] - m); s += p[e]; }
    float inv = 1.f / s;
    #pragma unroll
    for (int e = 0; e < 8; ++e) p[e] *= inv;
    float p1 = -1.f, p2 = -1.f; int i1 = 0, i2 = 0;
    #pragma unroll
    for (int e = 0; e < 8; ++e) {
        float pe = p[e];
        if (pe > p1) { p2 = p1; i2 = i1; p1 = pe; i1 = e; }
        else if (pe > p2) { p2 = pe; i2 = e; }
    }
    float ee = expf(p2 - p1);
    float wa = 1.f / (1.f + ee);
    float wb = ee / (1.f + ee);
    if (l == 0) {
        #pragma unroll
        for (int e = 0; e < 8; ++e) gate_prob[(long)t * 8 + e] = p[e];
        #pragma unroll
        for (int e = 0; e < 8; ++e) impL[w][e] = p[e];
        choice[t] = i1 | (i2 << 8);
        w12[t] = make_float2(wa, wb);
    }
    __syncthreads();
    if (threadIdx.x < 8)
        impP[blockIdx.x * 8 + threadIdx.x] =
            impL[0][threadIdx.x] + impL[1][threadIdx.x] +
            impL[2][threadIdx.x] + impL[3][threadIdx.x];
}

// ---------------- sorted routing: histogram -> scan -> stable scatter ----------------
__global__ __launch_bounds__(256) void k_hist(const int* __restrict__ choice,
                                              int* __restrict__ bcnt) {
    __shared__ int cnt[8];
    if (threadIdx.x < 8) cnt[threadIdx.x] = 0;
    __syncthreads();
    int ch = choice[blockIdx.x * 256 + threadIdx.x];
    atomicAdd(&cnt[ch & 255], 1);
    atomicAdd(&cnt[(ch >> 8) & 255], 1);
    __syncthreads();
    if (threadIdx.x < 8) bcnt[blockIdx.x * 8 + threadIdx.x] = cnt[threadIdx.x];
}

__global__ __launch_bounds__(512) void k_scan(const int* __restrict__ bcnt,
                                              int* __restrict__ bbase,
                                              int* __restrict__ counts) {
    int w = threadIdx.x >> 6, l = threadIdx.x & 63;   // wave w = expert w
    int v = bcnt[l * 8 + w];
    int s = v;
    #pragma unroll
    for (int off = 1; off < 64; off <<= 1) {
        int o = __shfl_up(s, off);
        if (l >= off) s += o;
    }
    bbase[l * 8 + w] = s - v;
    if (l == 63) counts[w] = s;
}

__global__ __launch_bounds__(256) void k_scatter(const int* __restrict__ choice,
                                                 const float2* __restrict__ w12,
                                                 const int* __restrict__ bbase,
                                                 int* __restrict__ tok,
                                                 float* __restrict__ wgt) {
    __shared__ int wsum[4];
    int w = threadIdx.x >> 6, l = threadIdx.x & 63;
    int t = blockIdx.x * 256 + threadIdx.x;
    int ch = choice[t];
    int i1 = ch & 255, i2 = (ch >> 8) & 255;
    float2 ww = w12[t];
    for (int e = 0; e < 8; ++e) {
        bool f1 = (i1 == e), f2 = (i2 == e);
        bool f = f1 || f2;
        unsigned long long m = __ballot(f);
        int wl = __popcll(m & ((1ull << l) - 1ull));
        if (l == 0) wsum[w] = (int)__popcll(m);
        __syncthreads();
        int before = 0;
        #pragma unroll
        for (int j = 0; j < 4; ++j) before += (j < w) ? wsum[j] : 0;
        if (f) {
            int p = bbase[blockIdx.x * 8 + e] + before + wl;
            tok[e * Btok + p] = t;
            wgt[e * Btok + p] = f1 ? ww.x : ww.y;
        }
        __syncthreads();
    }
}

// ---------------- expert GEMMs: 128x128, BK=32, counted-vmcnt dbuf, 4 blocks/CU ----------------
// Double-buffered 2x(8KB A + 8KB B) = 32 KB LDS via global_load_lds (no VGPR staging,
// no spill). Queue holds 2 tiles (8 loads); vmcnt(4) at step top waits only for the
// tile staged one full step earlier (landed during prior compute) -> drain ~0, and
// co-resident blocks' lockstep becomes harmless. Raw s_barrier (no compiler vmcnt(0)).
// LDS rows 64B paired into 128B lines: line L holds rows L and L+64; 16B-slot pos of
// (half h, chunk c) = (h*4+c) ^ (L&7)  -> conflict-free-balanced b128 reads, and the
// gload dst stays linear (base + lane*16) with the inverse permutation on the SOURCE.
// MODE 0: H = bf16(silu(xb[tok] @ W1T + b1));  MODE 1: y[tok] += wgt*(H @ W2T + b2)
template <int MODE>
__global__ __launch_bounds__(256, 4) void k_gemm(const unsigned short* __restrict__ Abase,
                                                 const unsigned short* __restrict__ WT,
                                                 const float* __restrict__ bias,
                                                 const int* __restrict__ counts,
                                                 const int* __restrict__ tok,
                                                 const float* __restrict__ wgt,
                                                 unsigned short* __restrict__ Hout,
                                                 float* __restrict__ y) {
    __shared__ __align__(16) char lds[32768];   // A: buf0@0 buf1@8192 ; B: @16384,@24576
    char* ldsp = (char*)lds;

    int bid = blockIdx.x;                 // 4096 = 8e * 64rt * 8ct ; e=bid&7 -> XCD pin
    int e = bid & 7;
    int k = bid >> 3;
    int rt = k >> 3, ct = k & 7;

    int n_e = counts[e];
    int r0 = rt * 128;
    if (r0 >= n_e) return;
    int off_e = 0;
    #pragma unroll
    for (int j = 0; j < 8; ++j) off_e += (j < e) ? counts[j] : 0;
    int n0 = ct * 128;

    int t = threadIdx.x;
    int w = t >> 6, l = t & 63;
    int wm = w >> 1, wn = w & 1;          // wave tile 64x64
    int t16 = t * 16;

    // ---- staging sources: thread t, round r covers line L=(t>>3)+32r, slot p=t&7,
    //      which stores global (row L+64h, chunk c) with h*4+c = p ^ (L&7) ----
    const char* sA[2]; const char* sB[2];
    {
        int q = (t & 7) ^ ((t >> 3) & 7);
        int h = q >> 2, c = q & 3;
        #pragma unroll
        for (int r = 0; r < 2; ++r) {
            int rowl = (t >> 3) + 32 * r + 64 * h;
            int idx = r0 + rowl; if (idx > n_e - 1) idx = n_e - 1;
            long g = (MODE == 0) ? (long)tok[e * Btok + idx] : (long)(off_e + idx);
            sA[r] = (const char*)Abase + g * 2048 + c * 16;
            sB[r] = (const char*)WT + ((long)e << 21) + (long)(n0 + rowl) * 2048 + c * 16;
        }
    }

    // ---- fragment-read constants (inverse of the staging permutation) ----
    int rowb = (l & 15) * 128;
    int cpA = (((wm << 2) | (l >> 4)) ^ (l & 7)) << 4;
    int cpB = (((wn << 2) | (l >> 4)) ^ (l & 7)) << 4;

    f32x4 acc[4][4];
    #pragma unroll
    for (int mi = 0; mi < 4; ++mi)
        #pragma unroll
        for (int ni = 0; ni < 4; ++ni) acc[mi][ni] = {0.f, 0.f, 0.f, 0.f};

    // stage current-pointer K-tile into buffer b (4 gload16), advance pointers
    auto stage = [&](int b) {
        gload16(sA[0], ldsp + b * 8192 + t16);
        gload16(sA[1], ldsp + b * 8192 + 4096 + t16);
        gload16(sB[0], ldsp + 16384 + b * 8192 + t16);
        gload16(sB[1], ldsp + 16384 + b * 8192 + 4096 + t16);
        sA[0] += 64; sA[1] += 64; sB[0] += 64; sB[1] += 64;
    };
    auto compute = [&](int b) {
        const char* pA = ldsp + b * 8192 + rowb;
        const char* pB = ldsp + 16384 + b * 8192 + rowb;
        short8 av[4], bv[4];
        #pragma unroll
        for (int mi = 0; mi < 4; ++mi) av[mi] = *(const short8*)(pA + mi * 2048 + cpA);
        #pragma unroll
        for (int ni = 0; ni < 4; ++ni) bv[ni] = *(const short8*)(pB + ni * 2048 + cpB);
        __builtin_amdgcn_s_setprio(1);
        #pragma unroll
        for (int mi = 0; mi < 4; ++mi)
            #pragma unroll
            for (int ni = 0; ni < 4; ++ni)
                acc[mi][ni] = __builtin_amdgcn_mfma_f32_16x16x32_bf16(av[mi], bv[ni], acc[mi][ni], 0, 0, 0);
        __builtin_amdgcn_s_setprio(0);
    };

    // 32 K-tiles of BK=32; queue = 2 tiles (8 loads) in flight
    stage(0);                             // t0 -> buf0
    stage(1);                             // t1 -> buf1
    for (int kk = 0; kk < 31; ++kk) {
        VMW(4);                           // tile kk landed (next tile stays in flight)
        BARRIER();                        // all waves' loads for tile kk visible
        compute(kk & 1);
        BARRIER();                        // all waves done reading buf
        if (kk < 30) stage(kk & 1);       // tile kk+2 -> freed buffer
    }
    VMW(0); BARRIER();
    compute(1);                           // tile 31

    // ---- epilogue ----
    float bias4[4];
    #pragma unroll
    for (int ni = 0; ni < 4; ++ni)
        bias4[ni] = bias[e * Ddim + n0 + wn * 64 + ni * 16 + (l & 15)];

    #pragma unroll
    for (int mi = 0; mi < 4; ++mi) {
        #pragma unroll
        for (int j = 0; j < 4; ++j) {
            int rl = wm * 64 + mi * 16 + (l >> 4) * 4 + j;
            int r = r0 + rl;
            bool ok = r < n_e;
            int trow = 0; float wr = 0.f;
            if (MODE == 1) {
                int ri = ok ? r : 0;
                trow = tok[e * Btok + ri];
                wr = wgt[e * Btok + ri];
            }
            #pragma unroll
            for (int ni = 0; ni < 4; ++ni) {
                int col = n0 + wn * 64 + ni * 16 + (l & 15);
                float v = acc[mi][ni][j] + bias4[ni];
                if (MODE == 0) {
                    v = v / (1.f + __expf(-v));   // silu
                    if (ok) Hout[(long)(off_e + r) * Ddim + col] = f2bf(v);
                } else {
                    if (ok) atomicAdd(&y[(long)trow * Ddim + col], wr * v);
                }
            }
        }
    }
}

// ---------------- importance loss ----------------
__global__ __launch_bounds__(256) void k_loss(const float* __restrict__ impP,
                                              float* __restrict__ out) {
    __shared__ float red[256];
    __shared__ float impF[8];
    for (int e = 0; e < 8; ++e) {
        float s = 0.f;
        for (int i = threadIdx.x; i < 4096; i += 256) s += impP[i * 8 + e];
        red[threadIdx.x] = s;
        __syncthreads();
        for (int st = 128; st > 0; st >>= 1) {
            if ((int)threadIdx.x < st) red[threadIdx.x] += red[threadIdx.x + st];
            __syncthreads();
        }
        if (threadIdx.x == 0) impF[e] = red[0];
        __syncthreads();
    }
    if (threadIdx.x == 0) {
        double mean = 0.0;
        for (int e = 0; e < 8; ++e) mean += (double)impF[e];
        mean /= 8.0;
        double var = 0.0;
        for (int e = 0; e < 8; ++e) {
            double d = (double)impF[e] - mean;
            var += d * d;
        }
        var /= 7.0;   // ddof=1
        out[0] = (float)(0.01 * var / (mean * mean));
    }
}

// ---------------- launch ----------------
extern "C" void kernel_launch(void* const* d_in, const int* in_sizes, int n_in,
                              void* d_out, int out_size, void* d_ws, size_t ws_size,
                              hipStream_t stream) {
    const float* x  = (const float*)d_in[0];
    const float* q  = (const float*)d_in[1];
    const float* Wv = (const float*)d_in[2];
    const float* bv = (const float*)d_in[3];
    const float* Wo = (const float*)d_in[4];
    const float* bo = (const float*)d_in[5];
    const float* Wg = (const float*)d_in[6];
    const float* bg = (const float*)d_in[7];
    const float* W1 = (const float*)d_in[8];
    const float* b1 = (const float*)d_in[9];
    const float* W2 = (const float*)d_in[10];
    const float* b2 = (const float*)d_in[11];

    float* y = (float*)d_out;                       // [16384][1024]
    float* gate_prob = y + (long)Btok * Ddim;       // [16384][8]
    float* loss = gate_prob + (long)Btok * Eexp;    // [1]

    char* ws = (char*)d_ws;
    int*   counts = (int*)(ws + 0);                           // 32 B
    float* bcomb  = (float*)(ws + 256);                       // 32 B
    float* tmp    = (float*)(ws + 512);                       // 32 KB
    float* WcT    = (float*)(ws + 33280);                     // 32 KB
    float* impP   = (float*)(ws + 66048);                     // 128 KB
    int*   choice = (int*)(ws + 197120);                      // 64 KB
    float2* w12   = (float2*)(ws + 262656);                   // 128 KB
    int*   tok    = (int*)(ws + 393728);                      // 512 KB
    float* wgt    = (float*)(ws + 918016);                    // 512 KB
    int*   bcnt   = (int*)(ws + 1442304);                     // 2 KB
    int*   bbase  = (int*)(ws + 1444352);                     // 2 KB
    unsigned short* xb   = (unsigned short*)(ws + 1446912);   // 32 MB
    unsigned short* w1bT = (unsigned short*)(ws + 35001344);  // 16 MB
    unsigned short* w2bT = (unsigned short*)(ws + 51778560);  // 16 MB
    unsigned short* H    = (unsigned short*)(ws + 68555776);  // 64 MB

    hipMemsetAsync(y, 0, (size_t)Btok * Ddim * sizeof(float), stream);

    k_tmp<<<32, 256, 0, stream>>>(Wo, Wg, tmp);
    k_wc <<<32, 256, 0, stream>>>(Wv, tmp, WcT);
    k_bc <<<1, 512, 0, stream>>>(bv, bo, bg, Wg, tmp, bcomb);
    k_convx<<<16384, 256, 0, stream>>>((const float4*)x, (ushort4*)xb);
    k_convw<<<16384, 256, 0, stream>>>(W1, W2, w1bT, w2bT);
    k_gate<<<4096, 256, 0, stream>>>(q, WcT, bcomb, gate_prob, choice, w12, impP);
    k_hist<<<64, 256, 0, stream>>>(choice, bcnt);
    k_scan<<<1, 512, 0, stream>>>(bcnt, bbase, counts);
    k_scatter<<<64, 256, 0, stream>>>(choice, w12, bbase, tok, wgt);
    k_gemm<0><<<4096, 256, 0, stream>>>(xb, w1bT, b1, counts, tok, wgt, H, nullptr);
    k_gemm<1><<<4096, 256, 0, stream>>>(H, w2bT, b2, counts, tok, wgt, nullptr, y);
    k_loss<<<1, 256, 0, stream>>>(impP, loss);
}